// Round 1
// 278.226 us; speedup vs baseline: 1.0349x; 1.0349x over previous
//
#include <hip/hip_runtime.h>
#include <math.h>

// ---------- types ----------
typedef __attribute__((ext_vector_type(8))) __bf16 bf16x8;
typedef __attribute__((ext_vector_type(4))) float  f32x4;
typedef unsigned short ushort_t;
typedef unsigned int   uint_t;

static __device__ inline f32x4 mfma16(bf16x8 a, bf16x8 b, f32x4 c) {
    return __builtin_amdgcn_mfma_f32_16x16x32_bf16(a, b, c, 0, 0, 0);
}

static __device__ inline ushort_t f2b(float f) {
    uint_t u = __builtin_bit_cast(uint_t, f);
    u = (u + 0x7FFFu + ((u >> 16) & 1u)) >> 16;
    return (ushort_t)u;
}
static __device__ inline float b2f(ushort_t u) {
    uint_t x = ((uint_t)u) << 16;
    return __builtin_bit_cast(float, x);
}
static __device__ inline bf16x8 ld8(const ushort_t* p) {
    uint4 v = *(const uint4*)p;
    return __builtin_bit_cast(bf16x8, v);
}
static __device__ inline float fexp2(float x) {
#if __has_builtin(__builtin_amdgcn_exp2f)
    return __builtin_amdgcn_exp2f(x);
#else
    return exp2f(x);
#endif
}

// async global->LDS, 16B per lane; LDS dst = base + lane*16 (wave-uniform base!)
static __device__ inline void gl_lds16(const ushort_t* g, ushort_t* l) {
    __builtin_amdgcn_global_load_lds(
        (const __attribute__((address_space(1))) void*)(g),
        (__attribute__((address_space(3))) void*)(l),
        16, 0, 0);
}

// ---------- ws layout (peak = 62,914,560 B, same as R6) ----------
#define WS_XB     0          //  8 MiB x bf16           [2048,2048]   (dead after QKV gemm)
#define WS_WQKV   8388608    // 12 MiB [Wq;Wk;Wv] bf16  [3072,2048]   (dead after QKV gemm)
#define WS_WO     20971520   //  8 MiB Wo bf16          [2048,2048]
#define WS_P0     29360128   // 12 MiB QKV partial 0 bf16 [2048,3072] (dead after fuse)
#define WS_P1     41943040   // 12 MiB QKV partial 1 bf16 [2048,3072] (dead after fuse)
#define WS_QBB    0          //  8 MiB q roped bf16     (overlays xb)
#define WS_KBB    8388608    //  2 MiB k roped bf16     (overlays wqkvb head)
#define WS_VTG    10485760   //  2 MiB V^T bf16 [512,2048]
#define WS_AB     12582912   //  8 MiB attn out bf16    (ends exactly at WS_WO)
#define WS_O0     29360128   // 16 MiB O partial 0 fp32 (overlays p0)
#define WS_O1     46137344   // 16 MiB O partial 1 fp32 (ends 62914560)

// ---------- fp32 -> bf16 convert for x|Wq|Wk|Wv|Wo (contiguous dst) ----------
__global__ __launch_bounds__(256) void cvt_all(const float* __restrict__ x,
                                               const float* __restrict__ wq,
                                               const float* __restrict__ wk,
                                               const float* __restrict__ wv,
                                               const float* __restrict__ wo,
                                               ushort_t* __restrict__ dst) {
    const size_t i = (size_t)(blockIdx.x * 256 + threadIdx.x) * 4;
    const float* src; size_t off;
    if (i < 4194304)       { src = x;  off = 0; }
    else if (i < 8388608)  { src = wq; off = 4194304; }
    else if (i < 9437184)  { src = wk; off = 8388608; }
    else if (i < 10485760) { src = wv; off = 9437184; }
    else                   { src = wo; off = 10485760; }
    float4 v = *(const float4*)(src + (i - off));
    ushort4 o;
    o.x = f2b(v.x); o.y = f2b(v.y); o.z = f2b(v.z); o.w = f2b(v.w);
    *(ushort4*)(dst + i) = o;
}

// ---------- GEMM-NT tile body, m97-style (proven R3/R6) ----------
// 128x128, BK=64, async LDS staging, K-range [kbeg,kend). As/Bs: 8192 ushorts.
template <int OUTB>
static __device__ void gemm_tile(const ushort_t* __restrict__ A,
                                 const ushort_t* __restrict__ Bt,
                                 void* __restrict__ Cout,
                                 int N, int K, long m0, long n0,
                                 int kbeg, int kend,
                                 ushort_t* As, ushort_t* Bs) {
    const int tid  = threadIdx.x;
    const int lane = tid & 63, wave = tid >> 6;
    const int wr = wave >> 1, wc = wave & 1;
    const int qn = lane & 15, quad = lane >> 4;

    const ushort_t* ga = A  + (m0 + lane) * K + wave * 8;
    const ushort_t* gb = Bt + (n0 + lane) * K + wave * 8;
    ushort_t* laL = As + wave * 1024;
    ushort_t* laH = As + (wave + 4) * 1024;
    ushort_t* lbL = Bs + wave * 1024;
    ushort_t* lbH = Bs + (wave + 4) * 1024;

    f32x4 zero = {0.f, 0.f, 0.f, 0.f};
    f32x4 acc[4][4];
    for (int i = 0; i < 4; i++)
        for (int j = 0; j < 4; j++) acc[i][j] = zero;

    const long r64 = 64L * K;
    for (int k0 = kbeg; k0 < kend; k0 += 64) {
        __syncthreads();
        gl_lds16(ga + k0,            laL);
        gl_lds16(ga + r64 + k0,      laL + 512);
        gl_lds16(ga + k0 + 32,       laH);
        gl_lds16(ga + r64 + k0 + 32, laH + 512);
        gl_lds16(gb + k0,            lbL);
        gl_lds16(gb + r64 + k0,      lbL + 512);
        gl_lds16(gb + k0 + 32,       lbH);
        gl_lds16(gb + r64 + k0 + 32, lbH + 512);
        __syncthreads();
        #pragma unroll
        for (int kk = 0; kk < 2; kk++) {
            bf16x8 af[4], bfr[4];
            const int cb = (kk * 4 + quad) * 1024;
            #pragma unroll
            for (int i = 0; i < 4; i++)
                af[i] = *(const bf16x8*)(As + cb + (wr * 64 + i * 16 + qn) * 8);
            #pragma unroll
            for (int j = 0; j < 4; j++)
                bfr[j] = *(const bf16x8*)(Bs + cb + (wc * 64 + j * 16 + qn) * 8);
            #pragma unroll
            for (int i = 0; i < 4; i++)
                #pragma unroll
                for (int j = 0; j < 4; j++)
                    acc[i][j] = mfma16(af[i], bfr[j], acc[i][j]);
        }
    }
    #pragma unroll
    for (int i = 0; i < 4; i++)
        #pragma unroll
        for (int j = 0; j < 4; j++)
            #pragma unroll
            for (int r = 0; r < 4; r++) {
                long row = m0 + wr * 64 + i * 16 + quad * 4 + r;
                long col = n0 + wc * 64 + j * 16 + qn;
                if (OUTB)
                    ((ushort_t*)Cout)[row * N + col] = f2b(acc[i][j][r]);
                else
                    ((float*)Cout)[row * N + col] = acc[i][j][r];
            }
}

// ---------- split-K=2 GEMM wrapper: blockIdx.z picks K-half and dest slab ----------
template <int OUTB>
__global__ __launch_bounds__(256) void gemm_split(const ushort_t* __restrict__ A,
                                                  const ushort_t* __restrict__ Bt,
                                                  void* __restrict__ C0,
                                                  void* __restrict__ C1,
                                                  int N, int K) {
    __shared__ ushort_t As[8192];
    __shared__ ushort_t Bs[8192];
    const int half = blockIdx.z;
    const int kh = K >> 1;
    gemm_tile<OUTB>(A, Bt, half ? C1 : C0, N, K,
                    (long)blockIdx.y * 128, (long)blockIdx.x * 128,
                    half * kh, half * kh + kh, As, Bs);
}

// ---------- fused combine + RoPE + V-transpose ----------
// Reads bf16 partial slabs p0,p1 [2048,3072]; q cols 0..2047 -> rope*scale -> qd,
// k cols 2048..2559 -> rope -> kd, v cols 2560..3071 -> transpose -> vt[512][2048].
// Grid: (48 col-tiles, 32 row-tiles), 256 thr; each block = 64 rows x 64 cols.
__global__ __launch_bounds__(256) void fuse_crv(const ushort_t* __restrict__ p0,
                                                const ushort_t* __restrict__ p1,
                                                const float* __restrict__ cs,
                                                const float* __restrict__ sn,
                                                ushort_t* __restrict__ qd,
                                                ushort_t* __restrict__ kd,
                                                ushort_t* __restrict__ vt) {
    __shared__ ushort_t tl[64][65];
    const int cx = blockIdx.x;               // 0..47
    const int ty = blockIdx.y;               // 0..31
    const int r  = threadIdx.x >> 2;         // 0..63
    const int c0 = (threadIdx.x & 3) << 4;   // 0,16,32,48
    const int t  = ty * 64 + r;
    const size_t base = (size_t)t * 3072 + cx * 64;

    if (cx < 40) {                           // q or k: combine + rope
        const int cp = c0 ^ 32;
        float own[16], par[16];
        #pragma unroll
        for (int jj = 0; jj < 2; jj++) {
            uint4 a = *(const uint4*)(p0 + base + c0 + jj * 8);
            uint4 b = *(const uint4*)(p1 + base + c0 + jj * 8);
            uint4 c = *(const uint4*)(p0 + base + cp + jj * 8);
            uint4 d = *(const uint4*)(p1 + base + cp + jj * 8);
            const ushort_t* pa = (const ushort_t*)&a;
            const ushort_t* pb = (const ushort_t*)&b;
            const ushort_t* pc = (const ushort_t*)&c;
            const ushort_t* pd = (const ushort_t*)&d;
            #pragma unroll
            for (int e = 0; e < 8; e++) {
                own[jj * 8 + e] = b2f(pa[e]) + b2f(pb[e]);
                par[jj * 8 + e] = b2f(pc[e]) + b2f(pd[e]);
            }
        }
        float cs16[16], sn16[16];
        #pragma unroll
        for (int jj = 0; jj < 4; jj++) {
            float4 c4 = *(const float4*)(cs + (size_t)t * 64 + c0 + jj * 4);
            float4 s4 = *(const float4*)(sn + (size_t)t * 64 + c0 + jj * 4);
            cs16[jj * 4 + 0] = c4.x; cs16[jj * 4 + 1] = c4.y;
            cs16[jj * 4 + 2] = c4.z; cs16[jj * 4 + 3] = c4.w;
            sn16[jj * 4 + 0] = s4.x; sn16[jj * 4 + 1] = s4.y;
            sn16[jj * 4 + 2] = s4.z; sn16[jj * 4 + 3] = s4.w;
        }
        const float scale = (cx < 32) ? 0.18033688f : 1.0f;  // q: (1/8)*log2e
        union { ushort_t u[16]; uint4 v[2]; } o;
        #pragma unroll
        for (int j = 0; j < 16; j++) {
            const int d = c0 + j;
            const float pr = (d < 32) ? -par[j] : par[j];
            o.u[j] = f2b((own[j] * cs16[j] + pr * sn16[j]) * scale);
        }
        if (cx < 32) {
            ushort_t* dst = qd + (size_t)t * 2048 + cx * 64 + c0;
            *(uint4*)dst = o.v[0]; *(uint4*)(dst + 8) = o.v[1];
        } else {
            ushort_t* dst = kd + (size_t)t * 512 + (cx - 32) * 64 + c0;
            *(uint4*)dst = o.v[0]; *(uint4*)(dst + 8) = o.v[1];
        }
    } else {                                 // v: combine + transpose via LDS
        #pragma unroll
        for (int jj = 0; jj < 2; jj++) {
            uint4 a = *(const uint4*)(p0 + base + c0 + jj * 8);
            uint4 b = *(const uint4*)(p1 + base + c0 + jj * 8);
            const ushort_t* pa = (const ushort_t*)&a;
            const ushort_t* pb = (const ushort_t*)&b;
            #pragma unroll
            for (int e = 0; e < 8; e++)
                tl[r][c0 + jj * 8 + e] = f2b(b2f(pa[e]) + b2f(pb[e]));
        }
        __syncthreads();
        const int rr  = threadIdx.x >> 3;        // 0..31
        const int cc8 = (threadIdx.x & 7) * 8;
        const int db = (cx - 40) * 64, tb = ty * 64;
        #pragma unroll
        for (int h = 0; h < 2; h++) {
            const int d = rr + h * 32;
            ushort4 o0, o1;
            o0.x = tl[cc8 + 0][d]; o0.y = tl[cc8 + 1][d];
            o0.z = tl[cc8 + 2][d]; o0.w = tl[cc8 + 3][d];
            o1.x = tl[cc8 + 4][d]; o1.y = tl[cc8 + 5][d];
            o1.z = tl[cc8 + 6][d]; o1.w = tl[cc8 + 7][d];
            *(ushort4*)(vt + (size_t)(db + d) * 2048 + tb + cc8)     = o0;
            *(ushort4*)(vt + (size_t)(db + d) * 2048 + tb + cc8 + 4) = o1;
        }
    }
}

// ---------- combine O partials -> fp32 out ----------
__global__ __launch_bounds__(256) void combine_o(const float4* __restrict__ s0,
                                                 const float4* __restrict__ s1,
                                                 float4* __restrict__ out) {
    for (int i = blockIdx.x * 256 + threadIdx.x; i < 1048576; i += 2048 * 256) {
        float4 a = s0[i], b = s1[i];
        float4 r; r.x = a.x + b.x; r.y = a.y + b.y; r.z = a.z + b.z; r.w = a.w + b.w;
        out[i] = r;
    }
}

// ---------- flash attention, causal, GQA G=4 ----------
// R7: occupancy/balance restructure.
//   - 64 q-rows per block (16 rows/wave), grid = 32 heads x 32 row-blocks = 1024.
//     Occupancy was grid-limited (512 blocks = 2/CU = 25% cap, measured 11.6%);
//     LDS drops 50->42 KB so 3 blocks/CU fit and the grid now supplies them.
//   - Heaviest block shrinks 32x(128x64) -> 32x(64x64) tiles: finer tail.
//   - P-scratch stride 72 -> 80 shorts: writes conflict-free (quad*40 mod 32 =
//     {0,8,16,24}), b128 reads drop 4-way -> 2-way.
__global__ __launch_bounds__(256) void attn_kernel(const ushort_t* __restrict__ Q,
                                                   const ushort_t* __restrict__ Kb,
                                                   const ushort_t* __restrict__ Vt,
                                                   ushort_t* __restrict__ Ob) {
    __shared__ ushort_t Ks[2 * 4096];     // 16 KB: [buf][chunk d/8][s-row 64][8]
    __shared__ ushort_t Vs[2 * 4096];     // 16 KB: [buf][chunk s/8][d-row 64][8]
    __shared__ ushort_t pl[4 * 16 * 80];  // 10 KB: per-wave P, 16 rows x 64 (stride 80)
    const int tid  = threadIdx.x;
    const int lane = tid & 63, wid = tid >> 6;
    const int qn = lane & 15, quad = lane >> 4;
    const int h   = blockIdx.x & 31;
    const int qb  = 31 - (blockIdx.x >> 5);     // heavy first, 0..31 (64-row blocks)
    const int kvb = (h >> 2) * 64;
    const int trow = qb * 64 + wid * 16;
    ushort_t* plw = pl + wid * 16 * 80;
    f32x4 zero = {0.f, 0.f, 0.f, 0.f};

    const ushort_t* qpA = Q + (size_t)(trow + qn) * 2048 + h * 64 + quad * 8;
    const bf16x8 qA0 = ld8(qpA), qA1 = ld8(qpA + 32);

    f32x4 oA[4] = {zero, zero, zero, zero};
    float lA[4] = {0.f, 0.f, 0.f, 0.f};
    const int ntiles = qb + 1;

#define STAGE(s0, buf)                                                         \
    do {                                                                       \
        const ushort_t* kg = Kb + (size_t)((s0) + lane) * 512 + kvb + wid * 8; \
        gl_lds16(kg,      Ks + (buf) * 4096 + wid * 512);                      \
        gl_lds16(kg + 32, Ks + (buf) * 4096 + (wid + 4) * 512);                \
        const ushort_t* vg = Vt + (size_t)(kvb + lane) * 2048 + (s0) + wid * 8;\
        gl_lds16(vg,      Vs + (buf) * 4096 + wid * 512);                      \
        gl_lds16(vg + 32, Vs + (buf) * 4096 + (wid + 4) * 512);                \
    } while (0)

#define COMPUTE(s0, buf)                                                       \
    do {                                                                       \
        f32x4 scA[4];                                                          \
        _Pragma("unroll")                                                      \
        for (int cb = 0; cb < 4; cb++) {                                       \
            const bf16x8 kf0 = *(const bf16x8*)(Ks + (buf) * 4096 + quad * 512 + (cb * 16 + qn) * 8);       \
            const bf16x8 kf1 = *(const bf16x8*)(Ks + (buf) * 4096 + (quad + 4) * 512 + (cb * 16 + qn) * 8); \
            f32x4 s = mfma16(qA0, kf0, zero); scA[cb] = mfma16(qA1, kf1, s);   \
        }                                                                      \
        const bool needmask = ((s0) + 63 > trow);                              \
        _Pragma("unroll")                                                      \
        for (int i = 0; i < 4; i++) {                                          \
            const int tA = trow + quad * 4 + i;                                \
            _Pragma("unroll")                                                  \
            for (int cb = 0; cb < 4; cb++) {                                   \
                const int col = (s0) + cb * 16 + qn;                           \
                float vA = scA[cb][i];                                         \
                if (needmask) {                                                \
                    if (col > tA) vA = -INFINITY;                              \
                }                                                              \
                const float pA = fexp2(vA);                                    \
                lA[i] += pA;                                                   \
                plw[(quad * 4 + i) * 80 + cb * 16 + qn] = f2b(pA);             \
            }                                                                  \
        }                                                                      \
        const bf16x8 pfA0 = *(const bf16x8*)(plw + qn * 80 + quad * 8);        \
        const bf16x8 pfA1 = *(const bf16x8*)(plw + qn * 80 + 32 + quad * 8);   \
        _Pragma("unroll")                                                      \
        for (int dcb = 0; dcb < 4; dcb++) {                                    \
            const bf16x8 vf0 = *(const bf16x8*)(Vs + (buf) * 4096 + quad * 512 + (dcb * 16 + qn) * 8);       \
            const bf16x8 vf1 = *(const bf16x8*)(Vs + (buf) * 4096 + (quad + 4) * 512 + (dcb * 16 + qn) * 8); \
            oA[dcb] = mfma16(pfA0, vf0, oA[dcb]);                              \
            oA[dcb] = mfma16(pfA1, vf1, oA[dcb]);                              \
        }                                                                      \
    } while (0)

    STAGE(0, 0);
    int t = 0;
    for (; t + 2 <= ntiles; t += 2) {
        __syncthreads();
        STAGE((t + 1) * 64, 1);
        COMPUTE(t * 64, 0);
        __syncthreads();
        if (t + 2 < ntiles) STAGE((t + 2) * 64, 0);
        COMPUTE((t + 1) * 64, 1);
    }
    if (t < ntiles) {                      // odd tail: buf0 already staged
        __syncthreads();
        COMPUTE(t * 64, 0);
    }
#undef STAGE
#undef COMPUTE

    #pragma unroll
    for (int i = 0; i < 4; i++) {
        float sA = lA[i];
        #pragma unroll
        for (int off = 1; off < 16; off <<= 1)
            sA += __shfl_xor(sA, off, 64);
        const float invA = 1.0f / sA;
        ushort_t* obA = Ob + (size_t)(trow + quad * 4 + i) * 2048 + h * 64 + qn;
        obA[0]  = f2b(oA[0][i] * invA);
        obA[16] = f2b(oA[1][i] * invA);
        obA[32] = f2b(oA[2][i] * invA);
        obA[48] = f2b(oA[3][i] * invA);
    }
}

// ---------- launch ----------
extern "C" void kernel_launch(void* const* d_in, const int* in_sizes, int n_in,
                              void* d_out, int out_size, void* d_ws, size_t ws_size,
                              hipStream_t stream) {
    const float* x    = (const float*)d_in[0];
    const float* cosp = (const float*)d_in[1];
    const float* sinp = (const float*)d_in[2];
    // d_in[3] = attention_mask_4d (pure causal; recomputed in-kernel)
    const float* Wq = (const float*)d_in[4];
    const float* Wk = (const float*)d_in[5];
    const float* Wv = (const float*)d_in[6];
    const float* Wo = (const float*)d_in[7];
    char* ws = (char*)d_ws;
    (void)ws_size; (void)in_sizes; (void)n_in; (void)out_size;

    ushort_t* xb    = (ushort_t*)(ws + WS_XB);
    ushort_t* wqkvb = (ushort_t*)(ws + WS_WQKV);
    ushort_t* wob   = (ushort_t*)(ws + WS_WO);
    ushort_t* p0    = (ushort_t*)(ws + WS_P0);
    ushort_t* p1    = (ushort_t*)(ws + WS_P1);
    ushort_t* qbb   = (ushort_t*)(ws + WS_QBB);
    ushort_t* kbb   = (ushort_t*)(ws + WS_KBB);
    ushort_t* vtg   = (ushort_t*)(ws + WS_VTG);
    ushort_t* ab    = (ushort_t*)(ws + WS_AB);
    float*    o0    = (float*)   (ws + WS_O0);
    float*    o1    = (float*)   (ws + WS_O1);

    // 1. convert inputs/weights to bf16 (contiguous dst: xb|wqkvb|wob)
    cvt_all<<<14336, 256, 0, stream>>>(x, Wq, Wk, Wv, Wo, xb);

    // 2. QKV projection split-K=2: 768 blocks (3/CU), bf16 partial slabs
    gemm_split<1><<<dim3(24, 16, 2), 256, 0, stream>>>(xb, wqkvb, p0, p1, 3072, 2048);

    // 3. fused combine + RoPE(q scale=(1/8)*log2e) + V transpose
    fuse_crv<<<dim3(48, 32), 256, 0, stream>>>(p0, p1, cosp, sinp, qbb, kbb, vtg);

    // 4. attention: 1024 blocks (4/CU supplied, 3/CU resident by LDS), 64 q-rows each
    attn_kernel<<<1024, 256, 0, stream>>>(qbb, kbb, vtg, ab);

    // 5. O-projection split-K=2: 512 blocks (2/CU), fp32 partial slabs
    gemm_split<0><<<dim3(16, 16, 2), 256, 0, stream>>>(ab, wob, o0, o1, 2048, 2048);

    // 6. combine partials into fp32 output
    combine_o<<<2048, 256, 0, stream>>>((const float4*)o0, (const float4*)o1,
                                        (float4*)d_out);
}